// Round 1
// 360.800 us; speedup vs baseline: 1.1591x; 1.1591x over previous
//
#include <hip/hip_runtime.h>
#include <hip/hip_bf16.h>
#include <stdint.h>

#define B_ROWS 4096
#define IN_F   4096
#define OUT_F  4096

// 256x256 tile, K-step 64, 8 waves (512 threads), 4 phases/K-tile.
#define BM 256
#define BN 256
#define BK 64
#define NKT (IN_F / BK)   // 64 K-tiles

typedef float  f32x4  __attribute__((ext_vector_type(4)));
typedef short  bf16x8 __attribute__((ext_vector_type(8)));
typedef unsigned short u16x4 __attribute__((ext_vector_type(4)));

#define AS1 __attribute__((address_space(1)))
#define AS3 __attribute__((address_space(3)))

__device__ __forceinline__ uint16_t f2bf_rne(float f) {
    uint32_t u = __float_as_uint(f);
    uint32_t r = u + 0x7fffu + ((u >> 16) & 1u);
    return (uint16_t)(r >> 16);
}
__device__ __forceinline__ float bf2f(uint16_t h) {
    return __uint_as_float(((uint32_t)h) << 16);
}

// Fused: x fp32 -> xb (bf16, row-major [b][k]) and xbT (bf16, transposed [k][b]).
__global__ __launch_bounds__(256) void cvt_x_t_kernel(
    const float* __restrict__ x, uint16_t* __restrict__ xb, uint16_t* __restrict__ xbT)
{
    __shared__ float t[64][65];
    const int r0 = blockIdx.y * 64;   // batch rows
    const int c0 = blockIdx.x * 64;   // feature cols
    const int tid = threadIdx.x;
    const int lr = tid >> 4;          // 0..15
    const int lc4 = (tid & 15) * 4;   // 0..60

#pragma unroll
    for (int p = 0; p < 4; ++p) {
        const int row = p * 16 + lr;
        float4 v = *(const float4*)(x + (size_t)(r0 + row) * IN_F + c0 + lc4);
        ushort4 o;
        o.x = f2bf_rne(v.x); o.y = f2bf_rne(v.y);
        o.z = f2bf_rne(v.z); o.w = f2bf_rne(v.w);
        *(ushort4*)(xb + (size_t)(r0 + row) * IN_F + c0 + lc4) = o;
        t[row][lc4 + 0] = v.x; t[row][lc4 + 1] = v.y;
        t[row][lc4 + 2] = v.z; t[row][lc4 + 3] = v.w;
    }
    __syncthreads();
#pragma unroll
    for (int p = 0; p < 4; ++p) {
        const int c = p * 16 + lr;    // source col -> dest row
        ushort4 o;
        o.x = f2bf_rne(t[lc4 + 0][c]);
        o.y = f2bf_rne(t[lc4 + 1][c]);
        o.z = f2bf_rne(t[lc4 + 2][c]);
        o.w = f2bf_rne(t[lc4 + 3][c]);
        *(ushort4*)(xbT + (size_t)(c0 + c) * B_ROWS + r0 + lc4) = o;
    }
}

// Sniff mask dtype over 1024 words.
__global__ void detect_mask_kernel(const uint32_t* __restrict__ mraw, int* __restrict__ flag) {
    __shared__ uint32_t red[256];
    uint32_t acc = 0;
    for (int k = threadIdx.x; k < 1024; k += 256) acc |= mraw[k];
    red[threadIdx.x] = acc;
    __syncthreads();
    for (int s = 128; s > 0; s >>= 1) {
        if (threadIdx.x < s) red[threadIdx.x] |= red[threadIdx.x + s];
        __syncthreads();
    }
    if (threadIdx.x == 0) *flag = (red[0] & 0xFFFFFF00u) ? 1 : 0;
}

// w fp32 + mask (dtype per *flag) -> masked bf16
__global__ void cvt_w_kernel(const float* __restrict__ w, const void* __restrict__ mraw,
                             const int* __restrict__ flag, uint16_t* __restrict__ wb) {
    int i = (blockIdx.x * 256 + threadIdx.x) * 4;
    float4 v = *(const float4*)(w + i);
    int m0, m1, m2, m3;
    if (*flag) {   // 1-byte bool mask
        uchar4 mm = *(const uchar4*)((const uint8_t*)mraw + i);
        m0 = mm.x; m1 = mm.y; m2 = mm.z; m3 = mm.w;
    } else {       // int32 0/1 mask
        int4 mm = *(const int4*)((const int*)mraw + i);
        m0 = mm.x; m1 = mm.y; m2 = mm.z; m3 = mm.w;
    }
    ushort4 o;
    o.x = m0 ? f2bf_rne(v.x) : (uint16_t)0;
    o.y = m1 ? f2bf_rne(v.y) : (uint16_t)0;
    o.z = m2 ? f2bf_rne(v.z) : (uint16_t)0;
    o.w = m3 ? f2bf_rne(v.w) : (uint16_t)0;
    *(ushort4*)(wb + i) = o;
}

// ---------------------------------------------------------------------------
// 256x256x64 phase-pipelined GEMM.
// C[b,o] = relu( sum_k xb[b,k]*wb[o,k] + bias[o] ) + xbT[rc[o]][b]
//
// LDS: A/B each 2 dbuf x 2 row-halves of [128][64] bf16 (16 KB per half-tile).
//   Half-tile LDS is LINEAR (global_load_lds requirement, rule 21); the
//   XOR-swizzle st pattern is applied on the per-lane GLOBAL source address
//   at stage time and the identical involution on the ds_read address:
//     16B-chunk slot s at row r holds global k-slot (s ^ (r&7)).
//   ds_read_b128 then spreads 64 lanes uniformly over all 32 banks.
//
// Schedule per K-tile t (4 phases, quadrants of the 256x256 C tile):
//   P1 (mh0,nh0): vmcnt(4); bar; read A0,B0;   stage A0(t+1); 16 MFMA
//   P2 (mh1,nh0): vmcnt(4); bar; read A1;      stage B0(t+1); 16 MFMA
//   P3 (mh1,nh1): vmcnt(4); bar; read B1;      stage A1(t+1); 16 MFMA
//   P4 (mh0,nh1):           bar; read A0;      stage B1(t+1); 16 MFMA
// Issue order A0,B0,A1,B1 makes every counted vmcnt(4) retire exactly the
// half-tiles the upcoming phase reads (2-3 half-tiles always in flight;
// never drains to 0 in the main loop).
// ---------------------------------------------------------------------------
__global__ __launch_bounds__(512, 2) void gemm_kernel(
    const uint16_t* __restrict__ xb, const uint16_t* __restrict__ wb,
    const uint16_t* __restrict__ xbT, const float* __restrict__ bias,
    const int* __restrict__ rc, float* __restrict__ out)
{
    __shared__ alignas(16) uint16_t Abuf[2][2][128 * BK];   // 64 KB
    __shared__ alignas(16) uint16_t Bbuf[2][2][128 * BK];   // 64 KB
    __shared__ float bias_s[BN];
    __shared__ int   rc_s[BN];

    const int tid = threadIdx.x;

    // XCD-aware bijective swizzle: 256 blocks, 8 XCDs; XCD x gets 2 full
    // tile-rows (A-panel 4MB = one XCD L2).
    const int bid = blockIdx.x;
    const int wg  = (bid & 7) * 32 + (bid >> 3);
    const int row0 = (wg >> 4) * BM;
    const int col0 = (wg & 15) * BN;

    const int wave = tid >> 6, lane = tid & 63;
    const int wm = wave >> 1;          // 0..3  (32-row slice inside a quadrant)
    const int wn = wave & 1;           // 0..1  (64-col slice inside a quadrant)
    const int quad = lane >> 4, l16 = lane & 15;
    const int swr = (l16 & 7) << 3;    // element-XOR for swizzled ds_read

    // Staging source (pre-swizzled global address, rule 21):
    // chunk c = tid + round*512; row = c>>3, slot = c&7; source k-chunk = slot^(row&7).
    const int srow = tid >> 3;                              // 0..63 (round 0)
    const int ssw  = ((tid & 7) ^ (srow & 7)) << 3;         // element offset
    const uint16_t* pA0 = xb + (size_t)(row0 + srow) * IN_F + ssw;
    const uint16_t* pB0 = wb + (size_t)(col0 + srow) * IN_F + ssw;
    const uint16_t* pA1 = pA0 + (size_t)128 * IN_F;
    const uint16_t* pB1 = pB0 + (size_t)128 * IN_F;

    auto stage = [&](const uint16_t* src, uint16_t* ldsdst, size_t ko) {
        __builtin_amdgcn_global_load_lds((const AS1 void*)(src + ko),
                                         (AS3 void*)(ldsdst + tid * 8), 16, 0, 0);
        __builtin_amdgcn_global_load_lds((const AS1 void*)(src + ko + (size_t)64 * IN_F),
                                         (AS3 void*)(ldsdst + tid * 8 + 4096), 16, 0, 0);
    };

    // bias/rc -> LDS via 4B global_load_lds (counted together with the
    // prologue stages; vmcnt(4) at t0.P1 retires them).
    if (tid < BN) {
        __builtin_amdgcn_global_load_lds((const AS1 void*)(bias + col0 + tid),
                                         (AS3 void*)(bias_s + tid), 4, 0, 0);
        __builtin_amdgcn_global_load_lds((const AS1 void*)(rc + col0 + tid),
                                         (AS3 void*)(rc_s + tid), 4, 0, 0);
    }

    f32x4 acc[4][2][4];   // [quadrant][mi][ni]
#pragma unroll
    for (int q = 0; q < 4; ++q)
#pragma unroll
        for (int mi = 0; mi < 2; ++mi)
#pragma unroll
            for (int ni = 0; ni < 4; ++ni)
                acc[q][mi][ni] = (f32x4){0.f, 0.f, 0.f, 0.f};

    // Prologue: stage tile 0 (issue order A0,B0,A1,B1).
    stage(pA0, &Abuf[0][0][0], 0);
    stage(pB0, &Bbuf[0][0][0], 0);
    stage(pA1, &Abuf[0][1][0], 0);
    stage(pB1, &Bbuf[0][1][0], 0);

    bf16x8 a[2][2];   // [mi][ks] current A half fragments
    bf16x8 b[4][2];   // [ni][ks] current B half fragments

#define WAIT_VM4() asm volatile("s_waitcnt vmcnt(4)" ::: "memory")
#define BARRIER()  do { __builtin_amdgcn_s_barrier(); asm volatile("" ::: "memory"); } while (0)

    for (int t = 0; t < NKT; ++t) {
        const int cur = t & 1, nxt = cur ^ 1;
        // t = NKT-1 stages one garbage K-tile past the end; reads land in the
        // adjacent workspace regions (wb/xbT) and the data is never consumed.
        const size_t koff = (size_t)(t + 1) * BK;

        auto load_a = [&](int mh) {
#pragma unroll
            for (int mi = 0; mi < 2; ++mi) {
                const int rA = wm * 32 + mi * 16 + l16;
#pragma unroll
                for (int ks = 0; ks < 2; ++ks)
                    a[mi][ks] = *(const bf16x8*)__builtin_assume_aligned(
                        (const void*)(&Abuf[cur][mh][rA * BK + ((ks * 32 + (quad << 3)) ^ swr)]), 16);
            }
        };
        auto load_b = [&](int nh) {
#pragma unroll
            for (int ni = 0; ni < 4; ++ni) {
                const int rB = wn * 64 + ni * 16 + l16;
#pragma unroll
                for (int ks = 0; ks < 2; ++ks)
                    b[ni][ks] = *(const bf16x8*)__builtin_assume_aligned(
                        (const void*)(&Bbuf[cur][nh][rB * BK + ((ks * 32 + (quad << 3)) ^ swr)]), 16);
            }
        };
        auto mfma_q = [&](int q) {
            __builtin_amdgcn_s_setprio(1);
#pragma unroll
            for (int mi = 0; mi < 2; ++mi)
#pragma unroll
                for (int ni = 0; ni < 4; ++ni) {
                    acc[q][mi][ni] = __builtin_amdgcn_mfma_f32_16x16x32_bf16(
                        a[mi][0], b[ni][0], acc[q][mi][ni], 0, 0, 0);
                    acc[q][mi][ni] = __builtin_amdgcn_mfma_f32_16x16x32_bf16(
                        a[mi][1], b[ni][1], acc[q][mi][ni], 0, 0, 0);
                }
            __builtin_amdgcn_s_setprio(0);
        };

        // P1: quadrant (mh0, nh0)
        WAIT_VM4();
        BARRIER();
        load_a(0); load_b(0);
        stage(pA0, &Abuf[nxt][0][0], koff);
        mfma_q(0);

        // P2: quadrant (mh1, nh0) — reuse b
        WAIT_VM4();
        BARRIER();
        load_a(1);
        stage(pB0, &Bbuf[nxt][0][0], koff);
        mfma_q(1);

        // P3: quadrant (mh1, nh1) — reuse a
        WAIT_VM4();
        BARRIER();
        load_b(1);
        stage(pA1, &Abuf[nxt][1][0], koff);
        mfma_q(2);

        // P4: quadrant (mh0, nh1) — re-read A0 (already resident in LDS), reuse b
        BARRIER();
        load_a(0);
        stage(pB1, &Bbuf[nxt][1][0], koff);
        mfma_q(3);
    }

#undef WAIT_VM4
#undef BARRIER

    // Epilogue. C/D layout: col = lane&15, row = quad*4 + reg (m89-verified).
    const int QMH[4] = {0, 1, 1, 0};
    const int QNH[4] = {0, 0, 1, 1};
#pragma unroll
    for (int q = 0; q < 4; ++q) {
        const int mh = QMH[q], nh = QNH[q];
#pragma unroll
        for (int ni = 0; ni < 4; ++ni) {
            const int lcol = nh * 128 + wn * 64 + ni * 16 + l16;
            const int gcol = col0 + lcol;
            const float bv = bias_s[lcol];
            const int   rv = rc_s[lcol];
#pragma unroll
            for (int mi = 0; mi < 2; ++mi) {
                const int grow0 = row0 + mh * 128 + wm * 32 + mi * 16 + quad * 4;
                u16x4 xq = *(const u16x4*)(xbT + (size_t)rv * B_ROWS + grow0);
#pragma unroll
                for (int r = 0; r < 4; ++r) {
                    float v = fmaxf(acc[q][mi][ni][r] + bv, 0.0f) + bf2f(xq[r]);
                    out[(size_t)(grow0 + r) * OUT_F + gcol] = v;
                }
            }
        }
    }
}

extern "C" void kernel_launch(void* const* d_in, const int* in_sizes, int n_in,
                              void* d_out, int out_size, void* d_ws, size_t ws_size,
                              hipStream_t stream) {
    const float* x    = (const float*)d_in[0];
    const float* w    = (const float*)d_in[1];
    const float* bias = (const float*)d_in[2];
    const void*  mask = (const void*)d_in[3];
    const int*   rc   = (const int*)d_in[4];
    float* out = (float*)d_out;

    uint16_t* xb   = (uint16_t*)d_ws;                      // 32 MB
    uint16_t* wb   = xb  + (size_t)B_ROWS * IN_F;          // 32 MB
    uint16_t* xbT  = wb  + (size_t)OUT_F * IN_F;           // 32 MB
    int*      flag = (int*)(xbT + (size_t)IN_F * B_ROWS);  // 4 B

    detect_mask_kernel<<<1, 256, 0, stream>>>((const uint32_t*)mask, flag);
    {
        dim3 g(IN_F / 64, B_ROWS / 64);
        cvt_x_t_kernel<<<g, 256, 0, stream>>>(x, xb, xbT);
    }
    cvt_w_kernel<<<(OUT_F * IN_F) / (256 * 4), 256, 0, stream>>>(w, mask, flag, wb);

    gemm_kernel<<<dim3((B_ROWS / BM) * (OUT_F / BN)), dim3(512), 0, stream>>>(
        xb, wb, xbT, bias, rc, out);
}

// Round 2
// 350.896 us; speedup vs baseline: 1.1919x; 1.0282x over previous
//
#include <hip/hip_runtime.h>
#include <hip/hip_bf16.h>
#include <stdint.h>

#define B_ROWS 4096
#define IN_F   4096
#define OUT_F  4096

// 256x256 tile, K-step 64, 8 waves (512 threads), 4 phases/K-tile.
#define BM 256
#define BN 256
#define BK 64
#define NKT (IN_F / BK)   // 64 K-tiles

typedef float  f32x4  __attribute__((ext_vector_type(4)));
typedef short  bf16x8 __attribute__((ext_vector_type(8)));
typedef unsigned short u16x4 __attribute__((ext_vector_type(4)));

#define AS1 __attribute__((address_space(1)))
#define AS3 __attribute__((address_space(3)))

template<int N> struct IC { static constexpr int v = N; };

__device__ __forceinline__ uint16_t f2bf_rne(float f) {
    uint32_t u = __float_as_uint(f);
    uint32_t r = u + 0x7fffu + ((u >> 16) & 1u);
    return (uint16_t)(r >> 16);
}
__device__ __forceinline__ float bf2f(uint16_t h) {
    return __uint_as_float(((uint32_t)h) << 16);
}

// Fused: x fp32 -> xb (bf16, row-major [b][k]) and xbT (bf16, transposed [k][b]).
__global__ __launch_bounds__(256) void cvt_x_t_kernel(
    const float* __restrict__ x, uint16_t* __restrict__ xb, uint16_t* __restrict__ xbT)
{
    __shared__ float t[64][65];
    const int r0 = blockIdx.y * 64;   // batch rows
    const int c0 = blockIdx.x * 64;   // feature cols
    const int tid = threadIdx.x;
    const int lr = tid >> 4;          // 0..15
    const int lc4 = (tid & 15) * 4;   // 0..60

#pragma unroll
    for (int p = 0; p < 4; ++p) {
        const int row = p * 16 + lr;
        float4 v = *(const float4*)(x + (size_t)(r0 + row) * IN_F + c0 + lc4);
        ushort4 o;
        o.x = f2bf_rne(v.x); o.y = f2bf_rne(v.y);
        o.z = f2bf_rne(v.z); o.w = f2bf_rne(v.w);
        *(ushort4*)(xb + (size_t)(r0 + row) * IN_F + c0 + lc4) = o;
        t[row][lc4 + 0] = v.x; t[row][lc4 + 1] = v.y;
        t[row][lc4 + 2] = v.z; t[row][lc4 + 3] = v.w;
    }
    __syncthreads();
#pragma unroll
    for (int p = 0; p < 4; ++p) {
        const int c = p * 16 + lr;    // source col -> dest row
        ushort4 o;
        o.x = f2bf_rne(t[lc4 + 0][c]);
        o.y = f2bf_rne(t[lc4 + 1][c]);
        o.z = f2bf_rne(t[lc4 + 2][c]);
        o.w = f2bf_rne(t[lc4 + 3][c]);
        *(ushort4*)(xbT + (size_t)(c0 + c) * B_ROWS + r0 + lc4) = o;
    }
}

// Sniff mask dtype over 1024 words.
__global__ void detect_mask_kernel(const uint32_t* __restrict__ mraw, int* __restrict__ flag) {
    __shared__ uint32_t red[256];
    uint32_t acc = 0;
    for (int k = threadIdx.x; k < 1024; k += 256) acc |= mraw[k];
    red[threadIdx.x] = acc;
    __syncthreads();
    for (int s = 128; s > 0; s >>= 1) {
        if (threadIdx.x < s) red[threadIdx.x] |= red[threadIdx.x + s];
        __syncthreads();
    }
    if (threadIdx.x == 0) *flag = (red[0] & 0xFFFFFF00u) ? 1 : 0;
}

// w fp32 + mask (dtype per *flag) -> masked bf16
__global__ void cvt_w_kernel(const float* __restrict__ w, const void* __restrict__ mraw,
                             const int* __restrict__ flag, uint16_t* __restrict__ wb) {
    int i = (blockIdx.x * 256 + threadIdx.x) * 4;
    float4 v = *(const float4*)(w + i);
    int m0, m1, m2, m3;
    if (*flag) {   // 1-byte bool mask
        uchar4 mm = *(const uchar4*)((const uint8_t*)mraw + i);
        m0 = mm.x; m1 = mm.y; m2 = mm.z; m3 = mm.w;
    } else {       // int32 0/1 mask
        int4 mm = *(const int4*)((const int*)mraw + i);
        m0 = mm.x; m1 = mm.y; m2 = mm.z; m3 = mm.w;
    }
    ushort4 o;
    o.x = m0 ? f2bf_rne(v.x) : (uint16_t)0;
    o.y = m1 ? f2bf_rne(v.y) : (uint16_t)0;
    o.z = m2 ? f2bf_rne(v.z) : (uint16_t)0;
    o.w = m3 ? f2bf_rne(v.w) : (uint16_t)0;
    *(ushort4*)(wb + i) = o;
}

__device__ __forceinline__ bf16x8 ds_read128(uint32_t off) {
    bf16x8 r;
    asm volatile("ds_read_b128 %0, %1" : "=v"(r) : "v"(off));
    return r;
}
#define LDSOFF(p) ((uint32_t)(uintptr_t)(AS3 void*)(p))

// ---------------------------------------------------------------------------
// 256x256x64 phase-pipelined GEMM — m201-template structure.
// C[b,o] = relu( sum_k xb[b,k]*wb[o,k] + bias[o] ) + xbT[rc[o]][b]
//
// Waves 2M x 4N: each wave owns 128 rows (half wm) x 64 cols. Per K-tile:
// B-frags (8) read ONCE in P0 and held in regs; A streamed as 4 mi-pairs.
// Phase = { asm ds_read; stage; s_barrier; lgkmcnt(0)+sched_barrier;
//           setprio(1); 16 MFMA; setprio(0); s_barrier }.
// ds_reads are inline asm so the compiler cannot order them against the
// outstanding global_load_lds queue (rule 18: lgkmcnt(0)+sched_barrier(0)
// before MFMA). One vmcnt(0) per K-tile at the dbuf swap: every outstanding
// load there is >=2 phases old, so the drain is free (not the per-phase
// drain-0 anti-pattern).
//
// LDS halves are LINEAR for global_load_lds (rule 21); the XOR swizzle is
// applied on the per-lane GLOBAL source address and identically on the
// ds_read address: 16B-chunk slot s at row r holds global k-chunk s^(r&7).
// ---------------------------------------------------------------------------
__global__ __launch_bounds__(512, 2) void gemm_kernel(
    const uint16_t* __restrict__ xb, const uint16_t* __restrict__ wb,
    const uint16_t* __restrict__ xbT, const float* __restrict__ bias,
    const int* __restrict__ rc, float* __restrict__ out)
{
    __shared__ alignas(16) uint16_t Abuf[2][2][128 * BK];   // 64 KB
    __shared__ alignas(16) uint16_t Bbuf[2][2][128 * BK];   // 64 KB
    __shared__ float bias_s[BN];
    __shared__ int   rc_s[BN];

    const int tid = threadIdx.x;

    // XCD-aware bijective swizzle: 256 blocks, 8 XCDs.
    const int bid = blockIdx.x;
    const int wg  = (bid & 7) * 32 + (bid >> 3);
    const int row0 = (wg >> 4) * BM;
    const int col0 = (wg & 15) * BN;

    const int wave = tid >> 6, lane = tid & 63;
    const int wm = wave >> 2;          // 0..1 : which 128-row A half
    const int wn = wave & 3;           // 0..3 : 64-col slice
    const int bh = wn >> 1;            // which 128-col B half
    const int quad = lane >> 4, l16 = lane & 15;
    const int swr = (l16 & 7) << 3;
    const int e0  = (quad << 3) ^ swr;                 // elem offset, ks=0
    const uint32_t kd = (uint32_t)(((e0 ^ 32) - e0) * 2); // byte delta ks0->ks1

    // Per-wave LDS read bases (byte offsets), one per dbuf parity.
    const uint32_t aOff0 = LDSOFF(&Abuf[0][wm][0]) + (uint32_t)((l16 * BK + e0) * 2);
    const uint32_t aOff1 = LDSOFF(&Abuf[1][wm][0]) + (uint32_t)((l16 * BK + e0) * 2);
    const uint32_t bOff0 = LDSOFF(&Bbuf[0][bh][0]) + (uint32_t)((((wn & 1) * 64 + l16) * BK + e0) * 2);
    const uint32_t bOff1 = LDSOFF(&Bbuf[1][bh][0]) + (uint32_t)((((wn & 1) * 64 + l16) * BK + e0) * 2);

    // Staging source (pre-swizzled global address, rule 21):
    // thread's chunk slot = tid&7, row = tid>>3; source k-chunk = slot^(row&7).
    const int srow = tid >> 3;                              // 0..63
    const int ssw  = ((tid & 7) ^ (srow & 7)) << 3;         // element offset
    const uint16_t* pA0 = xb + (size_t)(row0 + srow) * IN_F + ssw;
    const uint16_t* pB0 = wb + (size_t)(col0 + srow) * IN_F + ssw;
    const uint16_t* pA1 = pA0 + (size_t)128 * IN_F;
    const uint16_t* pB1 = pB0 + (size_t)128 * IN_F;

    auto stage = [&](const uint16_t* src, uint16_t* ldsdst, size_t ko) {
        __builtin_amdgcn_global_load_lds((const AS1 void*)(src + ko),
                                         (AS3 void*)(ldsdst + tid * 8), 16, 0, 0);
        __builtin_amdgcn_global_load_lds((const AS1 void*)(src + ko + (size_t)64 * IN_F),
                                         (AS3 void*)(ldsdst + tid * 8 + 4096), 16, 0, 0);
    };

    // bias/rc -> LDS (retired by the t=0 vmcnt(0)).
    if (tid < BN) {
        __builtin_amdgcn_global_load_lds((const AS1 void*)(bias + col0 + tid),
                                         (AS3 void*)(bias_s + tid), 4, 0, 0);
        __builtin_amdgcn_global_load_lds((const AS1 void*)(rc + col0 + tid),
                                         (AS3 void*)(rc_s + tid), 4, 0, 0);
    }

    f32x4 acc[8][4];   // [mi][ni]
#pragma unroll
    for (int mi = 0; mi < 8; ++mi)
#pragma unroll
        for (int ni = 0; ni < 4; ++ni)
            acc[mi][ni] = (f32x4){0.f, 0.f, 0.f, 0.f};

    // Prologue: stage tile 0.
    stage(pA0, &Abuf[0][0][0], 0);
    stage(pA1, &Abuf[0][1][0], 0);
    stage(pB0, &Bbuf[0][0][0], 0);
    stage(pB1, &Bbuf[0][1][0], 0);

#define LGKM0() do { asm volatile("s_waitcnt lgkmcnt(0)" ::: "memory"); \
                     __builtin_amdgcn_sched_barrier(0); } while (0)

    auto tile = [&](auto curc, int t) {
        constexpr int CUR = decltype(curc)::v;
        constexpr int NXT = CUR ^ 1;
        const uint32_t aB = CUR ? aOff1 : aOff0;
        const uint32_t bB = CUR ? bOff1 : bOff0;
        // t = NKT-1 stages one garbage K-tile past the end; the slight
        // overrun lands in adjacent workspace regions, never consumed.
        const size_t koff = (size_t)(t + 1) * BK;

        bf16x8 a[2][2], b[4][2];

        // ---- tile boundary: all 8 stages for this tile are >=2 phases old
        asm volatile("s_waitcnt vmcnt(0)" ::: "memory");
        __builtin_amdgcn_s_barrier();

        // ---- P0: all B-frags + A-pair 0; stage A halves of t+1
#pragma unroll
        for (int ni = 0; ni < 4; ++ni) {
            b[ni][0] = ds_read128(bB + ni * 2048);
            b[ni][1] = ds_read128(bB + ni * 2048 + kd);
        }
#pragma unroll
        for (int m2 = 0; m2 < 2; ++m2) {
            a[m2][0] = ds_read128(aB + m2 * 2048);
            a[m2][1] = ds_read128(aB + m2 * 2048 + kd);
        }
        stage(pA0, &Abuf[NXT][0][0], koff);
        stage(pA1, &Abuf[NXT][1][0], koff);
        __builtin_amdgcn_s_barrier();
        LGKM0();
        __builtin_amdgcn_s_setprio(1);
#pragma unroll
        for (int m2 = 0; m2 < 2; ++m2)
#pragma unroll
            for (int ni = 0; ni < 4; ++ni) {
                acc[m2][ni] = __builtin_amdgcn_mfma_f32_16x16x32_bf16(a[m2][0], b[ni][0], acc[m2][ni], 0, 0, 0);
                acc[m2][ni] = __builtin_amdgcn_mfma_f32_16x16x32_bf16(a[m2][1], b[ni][1], acc[m2][ni], 0, 0, 0);
            }
        __builtin_amdgcn_s_setprio(0);
        __builtin_amdgcn_s_barrier();

        // ---- P1: A-pair 1; stage B halves of t+1
#pragma unroll
        for (int m2 = 0; m2 < 2; ++m2) {
            a[m2][0] = ds_read128(aB + (2 + m2) * 2048);
            a[m2][1] = ds_read128(aB + (2 + m2) * 2048 + kd);
        }
        stage(pB0, &Bbuf[NXT][0][0], koff);
        stage(pB1, &Bbuf[NXT][1][0], koff);
        __builtin_amdgcn_s_barrier();
        LGKM0();
        __builtin_amdgcn_s_setprio(1);
#pragma unroll
        for (int m2 = 0; m2 < 2; ++m2)
#pragma unroll
            for (int ni = 0; ni < 4; ++ni) {
                acc[2 + m2][ni] = __builtin_amdgcn_mfma_f32_16x16x32_bf16(a[m2][0], b[ni][0], acc[2 + m2][ni], 0, 0, 0);
                acc[2 + m2][ni] = __builtin_amdgcn_mfma_f32_16x16x32_bf16(a[m2][1], b[ni][1], acc[2 + m2][ni], 0, 0, 0);
            }
        __builtin_amdgcn_s_setprio(0);
        __builtin_amdgcn_s_barrier();

        // ---- P2: A-pair 2
#pragma unroll
        for (int m2 = 0; m2 < 2; ++m2) {
            a[m2][0] = ds_read128(aB + (4 + m2) * 2048);
            a[m2][1] = ds_read128(aB + (4 + m2) * 2048 + kd);
        }
        __builtin_amdgcn_s_barrier();
        LGKM0();
        __builtin_amdgcn_s_setprio(1);
#pragma unroll
        for (int m2 = 0; m2 < 2; ++m2)
#pragma unroll
            for (int ni = 0; ni < 4; ++ni) {
                acc[4 + m2][ni] = __builtin_amdgcn_mfma_f32_16x16x32_bf16(a[m2][0], b[ni][0], acc[4 + m2][ni], 0, 0, 0);
                acc[4 + m2][ni] = __builtin_amdgcn_mfma_f32_16x16x32_bf16(a[m2][1], b[ni][1], acc[4 + m2][ni], 0, 0, 0);
            }
        __builtin_amdgcn_s_setprio(0);
        __builtin_amdgcn_s_barrier();

        // ---- P3: A-pair 3 (no trailing barrier; next tile's vmcnt+barrier)
#pragma unroll
        for (int m2 = 0; m2 < 2; ++m2) {
            a[m2][0] = ds_read128(aB + (6 + m2) * 2048);
            a[m2][1] = ds_read128(aB + (6 + m2) * 2048 + kd);
        }
        __builtin_amdgcn_s_barrier();
        LGKM0();
        __builtin_amdgcn_s_setprio(1);
#pragma unroll
        for (int m2 = 0; m2 < 2; ++m2)
#pragma unroll
            for (int ni = 0; ni < 4; ++ni) {
                acc[6 + m2][ni] = __builtin_amdgcn_mfma_f32_16x16x32_bf16(a[m2][0], b[ni][0], acc[6 + m2][ni], 0, 0, 0);
                acc[6 + m2][ni] = __builtin_amdgcn_mfma_f32_16x16x32_bf16(a[m2][1], b[ni][1], acc[6 + m2][ni], 0, 0, 0);
            }
        __builtin_amdgcn_s_setprio(0);
    };

    for (int tt = 0; tt < NKT; tt += 2) {
        tile(IC<0>{}, tt);
        tile(IC<1>{}, tt + 1);
    }
#undef LGKM0

    // Epilogue. C/D layout: col = lane&15, row = quad*4 + reg (m89-verified).
#pragma unroll
    for (int ni = 0; ni < 4; ++ni) {
        const int lcol = wn * 64 + ni * 16 + l16;
        const int gcol = col0 + lcol;
        const float bv = bias_s[lcol];
        const int   rv = rc_s[lcol];
#pragma unroll
        for (int mi = 0; mi < 8; ++mi) {
            const int grow0 = row0 + wm * 128 + mi * 16 + quad * 4;
            u16x4 xq = *(const u16x4*)(xbT + (size_t)rv * B_ROWS + grow0);
#pragma unroll
            for (int r = 0; r < 4; ++r) {
                float v = fmaxf(acc[mi][ni][r] + bv, 0.0f) + bf2f(xq[r]);
                out[(size_t)(grow0 + r) * OUT_F + gcol] = v;
            }
        }
    }
}

extern "C" void kernel_launch(void* const* d_in, const int* in_sizes, int n_in,
                              void* d_out, int out_size, void* d_ws, size_t ws_size,
                              hipStream_t stream) {
    const float* x    = (const float*)d_in[0];
    const float* w    = (const float*)d_in[1];
    const float* bias = (const float*)d_in[2];
    const void*  mask = (const void*)d_in[3];
    const int*   rc   = (const int*)d_in[4];
    float* out = (float*)d_out;

    uint16_t* xb   = (uint16_t*)d_ws;                      // 32 MB
    uint16_t* wb   = xb  + (size_t)B_ROWS * IN_F;          // 32 MB
    uint16_t* xbT  = wb  + (size_t)OUT_F * IN_F;           // 32 MB
    int*      flag = (int*)(xbT + (size_t)IN_F * B_ROWS);  // 4 B

    detect_mask_kernel<<<1, 256, 0, stream>>>((const uint32_t*)mask, flag);
    {
        dim3 g(IN_F / 64, B_ROWS / 64);
        cvt_x_t_kernel<<<g, 256, 0, stream>>>(x, xb, xbT);
    }
    cvt_w_kernel<<<(OUT_F * IN_F) / (256 * 4), 256, 0, stream>>>(w, mask, flag, wb);

    gemm_kernel<<<dim3((B_ROWS / BM) * (OUT_F / BN)), dim3(512), 0, stream>>>(
        xb, wb, xbT, bias, rc, out);
}

// Round 3
// 333.654 us; speedup vs baseline: 1.2535x; 1.0517x over previous
//
#include <hip/hip_runtime.h>
#include <hip/hip_bf16.h>
#include <stdint.h>

#define B_ROWS 4096
#define IN_F   4096
#define OUT_F  4096

// 256x256 tile, K-step 64, 8 waves (512 threads), 4 phases/K-tile.
#define BM 256
#define BN 256
#define BK 64
#define NKT (IN_F / BK)   // 64 K-tiles

typedef float  f32x4  __attribute__((ext_vector_type(4)));
typedef short  bf16x8 __attribute__((ext_vector_type(8)));
typedef unsigned short u16x4 __attribute__((ext_vector_type(4)));

#define AS1 __attribute__((address_space(1)))
#define AS3 __attribute__((address_space(3)))

template<int N> struct IC { static constexpr int v = N; };

__device__ __forceinline__ uint16_t f2bf_rne(float f) {
    uint32_t u = __float_as_uint(f);
    uint32_t r = u + 0x7fffu + ((u >> 16) & 1u);
    return (uint16_t)(r >> 16);
}
__device__ __forceinline__ float bf2f(uint16_t h) {
    return __uint_as_float(((uint32_t)h) << 16);
}

// ---------------------------------------------------------------------------
// Fused prep (one launch instead of three):
//   blocks [0, 4096):      x fp32 -> xb bf16 [b][k]  and xbT bf16 [k][b]
//   blocks [4096, 20480):  w fp32 + mask -> masked bf16 wb
// Mask dtype detected per-block from the first 256 mask words (L2-hot):
// int32 0/1 mask has upper 3 bytes zero in every word; a byte mask at 10%
// density has a nonzero upper byte in 768 bytes w.p. 1 - 0.9^768 ~ 1.
// ---------------------------------------------------------------------------
__global__ __launch_bounds__(256) void prep_kernel(
    const float* __restrict__ x, uint16_t* __restrict__ xb, uint16_t* __restrict__ xbT,
    const float* __restrict__ w, const void* __restrict__ mraw, uint16_t* __restrict__ wb)
{
    __shared__ float t[64][65];
    __shared__ int flag_s;
    const int tid = threadIdx.x;
    const int blk = blockIdx.x;

    if (blk < 4096) {
        // ---- x conversion + transpose (64x64 tile) ----
        const int r0 = (blk >> 6) * 64;   // batch rows
        const int c0 = (blk & 63) * 64;   // feature cols
        const int lr = tid >> 4;          // 0..15
        const int lc4 = (tid & 15) * 4;   // 0..60

#pragma unroll
        for (int p = 0; p < 4; ++p) {
            const int row = p * 16 + lr;
            float4 v = *(const float4*)(x + (size_t)(r0 + row) * IN_F + c0 + lc4);
            ushort4 o;
            o.x = f2bf_rne(v.x); o.y = f2bf_rne(v.y);
            o.z = f2bf_rne(v.z); o.w = f2bf_rne(v.w);
            *(ushort4*)(xb + (size_t)(r0 + row) * IN_F + c0 + lc4) = o;
            t[row][lc4 + 0] = v.x; t[row][lc4 + 1] = v.y;
            t[row][lc4 + 2] = v.z; t[row][lc4 + 3] = v.w;
        }
        __syncthreads();
#pragma unroll
        for (int p = 0; p < 4; ++p) {
            const int c = p * 16 + lr;    // source col -> dest row
            ushort4 o;
            o.x = f2bf_rne(t[lc4 + 0][c]);
            o.y = f2bf_rne(t[lc4 + 1][c]);
            o.z = f2bf_rne(t[lc4 + 2][c]);
            o.w = f2bf_rne(t[lc4 + 3][c]);
            *(ushort4*)(xbT + (size_t)(c0 + c) * B_ROWS + r0 + lc4) = o;
        }
    } else {
        // ---- w masking + conversion, with inline mask-dtype detect ----
        uint32_t mword = ((const uint32_t*)mraw)[tid];           // words 0..255, L2-hot
        unsigned long long bal = __ballot((mword & 0xFFFFFF00u) != 0);
        if (tid == 0) flag_s = 0;
        __syncthreads();
        if (bal != 0ull && (tid & 63) == 0) flag_s = 1;          // benign multi-write
        __syncthreads();
        const int flag = flag_s;

        const int i = ((blk - 4096) * 256 + tid) * 4;
        float4 v = *(const float4*)(w + i);
        int m0, m1, m2, m3;
        if (flag) {   // 1-byte bool mask
            uchar4 mm = *(const uchar4*)((const uint8_t*)mraw + i);
            m0 = mm.x; m1 = mm.y; m2 = mm.z; m3 = mm.w;
        } else {      // int32 0/1 mask
            int4 mm = *(const int4*)((const int*)mraw + i);
            m0 = mm.x; m1 = mm.y; m2 = mm.z; m3 = mm.w;
        }
        ushort4 o;
        o.x = m0 ? f2bf_rne(v.x) : (uint16_t)0;
        o.y = m1 ? f2bf_rne(v.y) : (uint16_t)0;
        o.z = m2 ? f2bf_rne(v.z) : (uint16_t)0;
        o.w = m3 ? f2bf_rne(v.w) : (uint16_t)0;
        *(ushort4*)(wb + i) = o;
    }
}

__device__ __forceinline__ bf16x8 ds_read128(uint32_t off) {
    bf16x8 r;
    asm volatile("ds_read_b128 %0, %1" : "=v"(r) : "v"(off));
    return r;
}
#define LDSOFF(p) ((uint32_t)(uintptr_t)(AS3 void*)(p))

// ---------------------------------------------------------------------------
// 256x256x64 free-running phase GEMM.
// C[b,o] = relu( sum_k xb[b,k]*wb[o,k] + bias[o] ) + xbT[rc[o]][b]
//
// R2 post-mortem: 2 barriers/phase locked all 8 waves into the same phase ->
// the CU's LDS burst (384-1150 cyc) and MFMA burst (620 cyc) executed
// back-to-back, serialized. This version keeps ONE s_barrier + ONE vmcnt(0)
// per K-tile (at the dbuf swap) and NO intra-tile barriers: waves free-run
// across the 4 phases, each gated only by its own lgkmcnt(0)+sched_barrier(0)
// before its MFMA cluster (rule 18). Wave skew overlaps LDS reads of some
// waves with MFMA of others; setprio(1) arbitrates in favor of MFMA waves.
//
// Correctness of single-barrier scheme:
//  - reads of tile t need all threads' stages for t landed: each thread does
//    vmcnt(0) BEFORE the boundary barrier => at release, whole tile resident.
//  - stages for t+1 (issued after the barrier) overwrite buf holding t-1
//    data: every wave retired its t-1 reads (per-phase lgkmcnt(0)) before
//    reaching that barrier.
//
// Phases are ks-major for even read sizes (8,4,8,4 per wave) and halved live
// B registers:  P0: ks0 mi0-3 (+stage A halves of t+1); P1: ks0 mi4-7
// (+stage B halves); P2: ks1 mi0-3; P3: ks1 mi4-7.
//
// LDS halves are LINEAR for global_load_lds (rule 21); XOR swizzle applied on
// the per-lane GLOBAL source address and identically on the ds_read address:
// 16B-chunk slot s at row r holds global k-chunk s^(r&7).
// ---------------------------------------------------------------------------
__global__ __launch_bounds__(512, 2) void gemm_kernel(
    const uint16_t* __restrict__ xb, const uint16_t* __restrict__ wb,
    const uint16_t* __restrict__ xbT, const float* __restrict__ bias,
    const int* __restrict__ rc, float* __restrict__ out)
{
    __shared__ alignas(16) uint16_t Abuf[2][2][128 * BK];   // 64 KB
    __shared__ alignas(16) uint16_t Bbuf[2][2][128 * BK];   // 64 KB
    __shared__ float bias_s[BN];
    __shared__ int   rc_s[BN];

    const int tid = threadIdx.x;

    // XCD-aware bijective swizzle: 256 blocks, 8 XCDs.
    const int bid = blockIdx.x;
    const int wg  = (bid & 7) * 32 + (bid >> 3);
    const int row0 = (wg >> 4) * BM;
    const int col0 = (wg & 15) * BN;

    const int wave = tid >> 6, lane = tid & 63;
    const int wm = wave >> 2;          // 0..1 : which 128-row A half
    const int wn = wave & 3;           // 0..3 : 64-col slice
    const int bh = wn >> 1;            // which 128-col B half
    const int quad = lane >> 4, l16 = lane & 15;
    const int swr = (l16 & 7) << 3;
    const int e0  = (quad << 3) ^ swr;                    // elem offset, ks=0
    const uint32_t kd = (uint32_t)(((e0 ^ 32) - e0) * 2); // byte delta ks0->ks1

    // Per-wave LDS read bases (byte offsets), one per dbuf parity.
    const uint32_t aOff0 = LDSOFF(&Abuf[0][wm][0]) + (uint32_t)((l16 * BK + e0) * 2);
    const uint32_t aOff1 = LDSOFF(&Abuf[1][wm][0]) + (uint32_t)((l16 * BK + e0) * 2);
    const uint32_t bOff0 = LDSOFF(&Bbuf[0][bh][0]) + (uint32_t)((((wn & 1) * 64 + l16) * BK + e0) * 2);
    const uint32_t bOff1 = LDSOFF(&Bbuf[1][bh][0]) + (uint32_t)((((wn & 1) * 64 + l16) * BK + e0) * 2);

    // Staging source (pre-swizzled global address, rule 21):
    // thread's chunk slot = tid&7, row = tid>>3; source k-chunk = slot^(row&7).
    const int srow = tid >> 3;                              // 0..63
    const int ssw  = ((tid & 7) ^ (srow & 7)) << 3;         // element offset
    const uint16_t* pA0 = xb + (size_t)(row0 + srow) * IN_F + ssw;
    const uint16_t* pB0 = wb + (size_t)(col0 + srow) * IN_F + ssw;
    const uint16_t* pA1 = pA0 + (size_t)128 * IN_F;
    const uint16_t* pB1 = pB0 + (size_t)128 * IN_F;

    auto stage = [&](const uint16_t* src, uint16_t* ldsdst, size_t ko) {
        __builtin_amdgcn_global_load_lds((const AS1 void*)(src + ko),
                                         (AS3 void*)(ldsdst + tid * 8), 16, 0, 0);
        __builtin_amdgcn_global_load_lds((const AS1 void*)(src + ko + (size_t)64 * IN_F),
                                         (AS3 void*)(ldsdst + tid * 8 + 4096), 16, 0, 0);
    };

    // bias/rc -> LDS (retired by the t=0 boundary vmcnt(0)).
    if (tid < BN) {
        __builtin_amdgcn_global_load_lds((const AS1 void*)(bias + col0 + tid),
                                         (AS3 void*)(bias_s + tid), 4, 0, 0);
        __builtin_amdgcn_global_load_lds((const AS1 void*)(rc + col0 + tid),
                                         (AS3 void*)(rc_s + tid), 4, 0, 0);
    }

    f32x4 acc[8][4];   // [mi][ni]
#pragma unroll
    for (int mi = 0; mi < 8; ++mi)
#pragma unroll
        for (int ni = 0; ni < 4; ++ni)
            acc[mi][ni] = (f32x4){0.f, 0.f, 0.f, 0.f};

    // Prologue: stage tile 0.
    stage(pA0, &Abuf[0][0][0], 0);
    stage(pA1, &Abuf[0][1][0], 0);
    stage(pB0, &Bbuf[0][0][0], 0);
    stage(pB1, &Bbuf[0][1][0], 0);

#define LGKM0() do { asm volatile("s_waitcnt lgkmcnt(0)" ::: "memory"); \
                     __builtin_amdgcn_sched_barrier(0); } while (0)

    auto tile = [&](auto curc, int t) {
        constexpr int CUR = decltype(curc)::v;
        constexpr int NXT = CUR ^ 1;
        const uint32_t aB = CUR ? aOff1 : aOff0;
        const uint32_t bB = CUR ? bOff1 : bOff0;
        // t = NKT-1 stages one garbage K-tile past the end; the slight
        // overrun lands in adjacent workspace regions, never consumed.
        const size_t koff = (size_t)(t + 1) * BK;

        bf16x8 a[4], b[4];

        // ---- tile boundary: the ONLY barrier+vmcnt of the tile.
        // Stages for this tile were issued >=2 phases ago -> drain ~free.
        asm volatile("s_waitcnt vmcnt(0)" ::: "memory");
        __builtin_amdgcn_s_barrier();
        __builtin_amdgcn_sched_barrier(0);

        // ---- P0: ks0, mi 0..3 ; stage A halves of t+1
#pragma unroll
        for (int ni = 0; ni < 4; ++ni) b[ni] = ds_read128(bB + ni * 2048);
#pragma unroll
        for (int m = 0; m < 4; ++m)   a[m]  = ds_read128(aB + m * 2048);
        stage(pA0, &Abuf[NXT][0][0], koff);
        stage(pA1, &Abuf[NXT][1][0], koff);
        LGKM0();
        __builtin_amdgcn_s_setprio(1);
#pragma unroll
        for (int m = 0; m < 4; ++m)
#pragma unroll
            for (int ni = 0; ni < 4; ++ni)
                acc[m][ni] = __builtin_amdgcn_mfma_f32_16x16x32_bf16(a[m], b[ni], acc[m][ni], 0, 0, 0);
        __builtin_amdgcn_s_setprio(0);

        // ---- P1: ks0, mi 4..7 ; stage B halves of t+1
#pragma unroll
        for (int m = 0; m < 4; ++m)   a[m] = ds_read128(aB + (4 + m) * 2048);
        stage(pB0, &Bbuf[NXT][0][0], koff);
        stage(pB1, &Bbuf[NXT][1][0], koff);
        LGKM0();
        __builtin_amdgcn_s_setprio(1);
#pragma unroll
        for (int m = 0; m < 4; ++m)
#pragma unroll
            for (int ni = 0; ni < 4; ++ni)
                acc[4 + m][ni] = __builtin_amdgcn_mfma_f32_16x16x32_bf16(a[m], b[ni], acc[4 + m][ni], 0, 0, 0);
        __builtin_amdgcn_s_setprio(0);

        // ---- P2: ks1, mi 0..3
#pragma unroll
        for (int ni = 0; ni < 4; ++ni) b[ni] = ds_read128(bB + ni * 2048 + kd);
#pragma unroll
        for (int m = 0; m < 4; ++m)   a[m]  = ds_read128(aB + m * 2048 + kd);
        LGKM0();
        __builtin_amdgcn_s_setprio(1);
#pragma unroll
        for (int m = 0; m < 4; ++m)
#pragma unroll
            for (int ni = 0; ni < 4; ++ni)
                acc[m][ni] = __builtin_amdgcn_mfma_f32_16x16x32_bf16(a[m], b[ni], acc[m][ni], 0, 0, 0);
        __builtin_amdgcn_s_setprio(0);

        // ---- P3: ks1, mi 4..7
#pragma unroll
        for (int m = 0; m < 4; ++m)   a[m] = ds_read128(aB + (4 + m) * 2048 + kd);
        LGKM0();
        __builtin_amdgcn_s_setprio(1);
#pragma unroll
        for (int m = 0; m < 4; ++m)
#pragma unroll
            for (int ni = 0; ni < 4; ++ni)
                acc[4 + m][ni] = __builtin_amdgcn_mfma_f32_16x16x32_bf16(a[m], b[ni], acc[4 + m][ni], 0, 0, 0);
        __builtin_amdgcn_s_setprio(0);
    };

    for (int tt = 0; tt < NKT; tt += 2) {
        tile(IC<0>{}, tt);
        tile(IC<1>{}, tt + 1);
    }
#undef LGKM0

    // Epilogue. C/D layout: col = lane&15, row = quad*4 + reg (m89-verified).
#pragma unroll
    for (int ni = 0; ni < 4; ++ni) {
        const int lcol = wn * 64 + ni * 16 + l16;
        const int gcol = col0 + lcol;
        const float bv = bias_s[lcol];
        const int   rv = rc_s[lcol];
#pragma unroll
        for (int mi = 0; mi < 8; ++mi) {
            const int grow0 = row0 + wm * 128 + mi * 16 + quad * 4;
            u16x4 xq = *(const u16x4*)(xbT + (size_t)rv * B_ROWS + grow0);
#pragma unroll
            for (int r = 0; r < 4; ++r) {
                float v = fmaxf(acc[mi][ni][r] + bv, 0.0f) + bf2f(xq[r]);
                out[(size_t)(grow0 + r) * OUT_F + gcol] = v;
            }
        }
    }
}

extern "C" void kernel_launch(void* const* d_in, const int* in_sizes, int n_in,
                              void* d_out, int out_size, void* d_ws, size_t ws_size,
                              hipStream_t stream) {
    const float* x    = (const float*)d_in[0];
    const float* w    = (const float*)d_in[1];
    const float* bias = (const float*)d_in[2];
    const void*  mask = (const void*)d_in[3];
    const int*   rc   = (const int*)d_in[4];
    float* out = (float*)d_out;

    uint16_t* xb   = (uint16_t*)d_ws;                      // 32 MB
    uint16_t* wb   = xb  + (size_t)B_ROWS * IN_F;          // 32 MB
    uint16_t* xbT  = wb  + (size_t)OUT_F * IN_F;           // 32 MB

    prep_kernel<<<4096 + 16384, 256, 0, stream>>>(x, xb, xbT, w, mask, wb);

    gemm_kernel<<<dim3((B_ROWS / BM) * (OUT_F / BN)), dim3(512), 0, stream>>>(
        xb, wb, xbT, bias, rc, out);
}